// Round 7
// baseline (1215.940 us; speedup 1.0000x reference)
//
#include <hip/hip_runtime.h>

#define NPT  4096
#define NBLK 256
#define NTHR 1024

constexpr float EPSV   = 1e-4f;
constexpr float LN2F   = 0.69314718055994531f;
constexpr float E2     = EPSV * LN2F;          // eps*ln2
constexpr float INV_E2 = 1.0f / E2;            // 1/(eps*ln2)
constexpr float S_U    = 4.0f / LN2F;          // uniformity scale

// LDS layout (floats), column-PAIR packed for v_pk_*_f32:
//   pAx : float4[2048] [0,8192)      (x0,x1,y0,y1) of x-point pairs
//   pBx : float4[2048] [8192,16384)  (z0,z1,G0,G1) of x-point pairs
//   pAy : float4[2048] [16384,24576) (x0,x1,y0,y1) of y-point pairs
//   pBy : float4[2048] [24576,32768) (z0,z1,G0,G1) of y-point pairs
//   part2: float2[1024] [32768,34816) per-row (m,s) partials [lrow][half*8+oct]
#define SMEM_FLOATS 34816
#define SMEM_BYTES  (SMEM_FLOATS * 4)

typedef float v2f __attribute__((ext_vector_type(2)));

__device__ __forceinline__ float fexp2(float x) { return __builtin_amdgcn_exp2f(x); }
__device__ __forceinline__ float flog2(float x) { return __builtin_amdgcn_logf(x); }

__device__ __forceinline__ v2f pk_fma(v2f a, v2f b, v2f c) {
    v2f d;
    asm("v_pk_fma_f32 %0, %1, %2, %3" : "=v"(d) : "v"(a), "v"(b), "v"(c));
    return d;
}
__device__ __forceinline__ float max3f(float a, float b, float c) {
    float d;
    asm("v_max3_f32 %0, %1, %2, %3" : "=v"(d) : "v"(a), "v"(b), "v"(c));
    return d;
}

// VALU-only cross-lane via DPP (no LDS pipe).
// 0xB1 = quad_perm [1,0,3,2] (xor1); 0x4E = quad_perm [2,3,0,1] (xor2);
// 0x141 = row_half_mirror (pairs quads within each 8-lane group).
template<int CTRL>
__device__ __forceinline__ float dppf(float x) {
    return __int_as_float(__builtin_amdgcn_update_dpp(
        __float_as_int(x), __float_as_int(x), CTRL, 0xF, 0xF, false));
}

// system-scope (sc0 sc1) relaxed accessors: bypass non-coherent XCD L2s.
__device__ __forceinline__ float gload(const float* p) {
    return __hip_atomic_load(p, __ATOMIC_RELAXED, __HIP_MEMORY_SCOPE_SYSTEM);
}
__device__ __forceinline__ void gstore(float* p, float v) {
    __hip_atomic_store(p, v, __ATOMIC_RELAXED, __HIP_MEMORY_SCOPE_SYSTEM);
}

// Fence-free GROUP barrier (128 blocks per group).
__device__ __forceinline__ void group_barrier(unsigned* base, unsigned target, int b) {
    asm volatile("s_waitcnt vmcnt(0)" ::: "memory");
    __syncthreads();
    if (threadIdx.x == 0) {
        __hip_atomic_fetch_add(&base[(b & 15) * 16], 1u,
                               __ATOMIC_RELAXED, __HIP_MEMORY_SCOPE_SYSTEM);
        for (;;) {
            unsigned tot = 0;
#pragma unroll
            for (int i = 0; i < 16; ++i)
                tot += __hip_atomic_load(&base[i * 16],
                                         __ATOMIC_RELAXED, __HIP_MEMORY_SCOPE_SYSTEM);
            if (tot >= target) break;
            __builtin_amdgcn_s_sleep(1);
        }
    }
    __syncthreads();
}

// One wave: ONLINE log2-LSE for 4 rows over 2048 columns (1024 pairs).
// Per pair: 2x ds_read_b128 (amortized over 4 rows); per pair per row:
// 3 pk_fma + max3 + 3 sub + 3 exp2 + add + fma. No chunk buffer (no spill).
// Reduction: 3-level DPP tree (VALU-only) -> 8 partials/row-half to LDS.
template<bool ISU>
__device__ __forceinline__ void run_task(
    const float4* __restrict__ cpA, const float4* __restrict__ cpB,
    const float*  __restrict__ rAf, const float*  __restrict__ rBf,
    int r0g, int half, int lane, float scale, float2* part2, int lr0)
{
    v2f xs0[4], xs1[4], xs2[4];
#pragma unroll
    for (int r = 0; r < 4; ++r) {
        const int rr = r0g + r;
        const int pb4 = (rr >> 1) * 4, c0 = rr & 1;
        float xv = rAf[pb4 + c0] * scale;
        float yv = rAf[pb4 + 2 + c0] * scale;
        float zv = rBf[pb4 + c0] * scale;
        xs0[r] = (v2f){xv, xv};
        xs1[r] = (v2f){yv, yv};
        xs2[r] = (v2f){zv, zv};
    }
    float m[4] = {-1e30f, -1e30f, -1e30f, -1e30f};
    float s[4] = {0.0f, 0.0f, 0.0f, 0.0f};

    const int pbase = half * 1024 + lane;
    const float4* colA = cpA + pbase;
    const float4* colB = cpB + pbase;

#pragma unroll
    for (int i = 0; i < 16; ++i) {
        const float4 a4 = colA[i * 64];
        const float4 b4 = colB[i * 64];
        const v2f xx = {a4.x, a4.y}, yy = {a4.z, a4.w};
        const v2f zz = {b4.x, b4.y}, gg = {b4.z, b4.w};
#pragma unroll
        for (int r = 0; r < 4; ++r) {
            v2f a01 = pk_fma(xs2[r], zz, gg);
            a01 = pk_fma(xs1[r], yy, a01);
            a01 = pk_fma(xs0[r], xx, a01);
            if (ISU) {
                const int p = pbase + i * 64;
                const int rr = r0g + r;
                if (p == (rr >> 1)) {
                    if (rr & 1) a01.y = -1e30f; else a01.x = -1e30f;
                }
            }
            const float mnew = max3f(m[r], a01.x, a01.y);
            const float es = fexp2(m[r] - mnew);
            const float e0 = fexp2(a01.x - mnew);
            const float e1 = fexp2(a01.y - mnew);
            s[r] = fmaf(s[r], es, e0 + e1);
            m[r] = mnew;
        }
    }

    // ---- VALU-only DPP reduction to 8-lane partials ----
#pragma unroll
    for (int r = 0; r < 4; ++r) {
        const float ml = m[r];
        float mm = m[r];
        mm = fmaxf(mm, dppf<0xB1>(mm));    // xor1
        mm = fmaxf(mm, dppf<0x4E>(mm));    // xor2
        mm = fmaxf(mm, dppf<0x141>(mm));   // quad<->quad within 8
        float ssv = s[r] * fexp2(ml - mm);
        ssv += dppf<0xB1>(ssv);
        ssv += dppf<0x4E>(ssv);
        ssv += dppf<0x141>(ssv);
        if ((lane & 7) == 0)
            part2[(lr0 + r) * 16 + half * 8 + (lane >> 3)] = make_float2(mm, ssv);
    }
}

__global__ void sink_init(float* __restrict__ ws) {
    int t = blockIdx.x * blockDim.x + threadIdx.x;
    if (t < NPT) {
        gstore(ws + t, 0.0f);           // f
        gstore(ws + 4096 + t, 0.0f);    // g
        gstore(ws + 8192 + t, 0.0f);    // px0
        gstore(ws + 16384 + t, 0.0f);   // py0
    }
    if (t < 512) {
        __hip_atomic_store((unsigned*)(ws + 40960) + t, 0u,
                           __ATOMIC_RELAXED, __HIP_MEMORY_SCOPE_SYSTEM);
    }
}

__global__ __launch_bounds__(NTHR)
__attribute__((amdgpu_waves_per_eu(4, 4)))
void sink_main(
    const float* __restrict__ xin, const float* __restrict__ yin,
    float* __restrict__ ws, float* __restrict__ out)
{
    extern __shared__ float smem[];
    float4* pAx = (float4*)smem;
    float4* pBx = (float4*)(smem + 8192);
    float4* pAy = (float4*)(smem + 16384);
    float4* pBy = (float4*)(smem + 24576);
    float2* part2 = (float2*)(smem + 32768);

    float* f    = ws;
    float* g    = ws + 4096;
    float* px0  = ws + 8192;
    float* px1  = ws + 12288;
    float* py0  = ws + 16384;
    float* py1  = ws + 20480;
    float* ffin = ws + 24576;
    float* fxv  = ws + 28672;
    float* fyv  = ws + 32768;
    float* uls  = ws + 36864;
    unsigned* ctrA = (unsigned*)(ws + 40960);        // group A (blocks 0-127)
    unsigned* ctrB = (unsigned*)(ws + 40960) + 256;  // group B (blocks 128-255)

    const int tid  = threadIdx.x;
    const int b    = blockIdx.x;
    const int wave = tid >> 6;
    const int lane = tid & 63;
    unsigned* cbarrier = (b < 128) ? ctrA : ctrB;

    // Stage point clouds into pair-packed LDS (G slots filled per step).
    const float4* yin4 = (const float4*)yin;
    for (int i = tid; i < 2048; i += NTHR) {
        float x0 = xin[6 * i + 0], y0v = xin[6 * i + 1], z0 = xin[6 * i + 2];
        float x1 = xin[6 * i + 3], y1v = xin[6 * i + 4], z1 = xin[6 * i + 5];
        pAx[i] = make_float4(x0, x1, y0v, y1v);
        pBx[i] = make_float4(z0, z1, 0.0f, 0.0f);
        float4 v0 = yin4[2 * i], v1 = yin4[2 * i + 1];
        pAy[i] = make_float4(v0.x, v1.x, v0.y, v1.y);
        pBy[i] = make_float4(v0.z, v1.z, 0.0f, 0.0f);
    }
    __syncthreads();

    for (int h = 0; h <= 40; ++h) {
        // ---- decode this block's chain for this step ----
        bool rows_x, cols_x, isU = false, avg = false;
        const float* pot; float* outp; float scale = INV_E2;
        int row0g, rows_pb;
        if (h == 0) {
            if (b < 128)      { rows_x = true;  cols_x = false; pot = g;    outp = f;    rows_pb = 32; row0g = b * 32; }
            else if (b < 192) { rows_x = true;  cols_x = true;  pot = px0;  outp = px1;  avg = true; rows_pb = 64; row0g = (b - 128) * 64; }
            else              { rows_x = true;  cols_x = true;  pot = nullptr; outp = uls; isU = true; scale = S_U; rows_pb = 64; row0g = (b - 192) * 64; }
        } else if (h == 40) {
            if (b < 128)      { rows_x = true;  cols_x = false; pot = g;    outp = ffin; rows_pb = 32; row0g = b * 32; }
            else if (b < 192) { rows_x = true;  cols_x = true;  pot = px0;  outp = fxv;  rows_pb = 64; row0g = (b - 128) * 64; }
            else              { rows_x = false; cols_x = false; pot = py0;  outp = fyv;  rows_pb = 64; row0g = (b - 192) * 64; }
        } else if (h & 1) {
            int k = (h - 1) >> 1;   // yy iteration
            if (b < 128) { rows_x = false; cols_x = true;  pot = f; outp = g; rows_pb = 32; row0g = b * 32; }
            else         { rows_x = false; cols_x = false; pot = (k & 1) ? py1 : py0; outp = (k & 1) ? py0 : py1; avg = true; rows_pb = 32; row0g = (b - 128) * 32; }
        } else {
            int k = h >> 1;         // xx iteration
            if (b < 128) { rows_x = true; cols_x = false; pot = g; outp = f; rows_pb = 32; row0g = b * 32; }
            else         { rows_x = true; cols_x = true;  pot = (k & 1) ? px1 : px0; outp = (k & 1) ? px0 : px1; avg = true; rows_pb = 32; row0g = (b - 128) * 32; }
        }

        // ---- restage G pair (pB[].zw) of the active column pack ----
        float4* cpA = cols_x ? pAx : pAy;
        float4* cpB = cols_x ? pBx : pBy;
        for (int p = tid; p < 2048; p += NTHR) {
            float4 a4 = cpA[p];
            float4 b4 = cpB[p];
            float cn0 = 0.5f * (a4.x * a4.x + a4.z * a4.z + b4.x * b4.x);
            float cn1 = 0.5f * (a4.y * a4.y + a4.w * a4.w + b4.y * b4.y);
            float pv0 = pot ? gload(pot + 2 * p)     : 0.0f;
            float pv1 = pot ? gload(pot + 2 * p + 1) : 0.0f;
            ((float2*)&cpB[p])[1] = make_float2((pv0 - cn0) * scale,
                                                (pv1 - cn1) * scale);
        }
        __syncthreads();

        // ---- wave tasks: 4 rows x 2048 cols each ----
        const float* rAf = (const float*)(rows_x ? pAx : pAy);
        const float* rBf = (const float*)(rows_x ? pBx : pBy);
        const int ntask = rows_pb >> 1;          // (rows_pb/4 groups) x 2 halves
        for (int t = wave; t < ntask; t += 16) {
            int grp = t >> 1, half = t & 1;
            int lr0 = grp << 2;
            int r0g = row0g + lr0;
            if (isU) run_task<true >(cpA, cpB, rAf, rBf, r0g, half, lane, scale, part2, lr0);
            else     run_task<false>(cpA, cpB, rAf, rBf, r0g, half, lane, scale, part2, lr0);
        }
        __syncthreads();

        // ---- finalize: merge 16 partials, apply row term, write potential ----
        if (tid < rows_pb) {
            float mm = -1e30f, ss = 0.0f;
#pragma unroll
            for (int q = 0; q < 16; ++q) {
                float2 p2 = part2[tid * 16 + q];
                float mn = fmaxf(mm, p2.x);
                ss = ss * fexp2(mm - mn) + p2.y * fexp2(p2.x - mn);
                mm = mn;
            }
            int rg = row0g + tid;
            const int pb4 = (rg >> 1) * 4, c0 = rg & 1;
            float xv = rAf[pb4 + c0];
            float yv = rAf[pb4 + 2 + c0];
            float zv = rBf[pb4 + c0];
            float rn = 0.5f * (xv * xv + yv * yv + zv * zv);
            float lse2 = mm + flog2(ss) - rn * scale;    // + X_i
            float val;
            if (isU) {
                val = lse2;
            } else {
                val = -E2 * (lse2 - 12.0f);               // log2(4096)=12
                if (avg) val = 0.5f * (gload(pot + rg) + val);
            }
            gstore(outp + rg, val);
        }

        group_barrier(cbarrier, 128u * (unsigned)(h + 1), b);
    }

    // ---- final reduction (block 0; must also wait for group B) ----
    if (b == 0) {
        if (tid == 0) {
            for (;;) {
                unsigned tot = 0;
#pragma unroll
                for (int i = 0; i < 16; ++i)
                    tot += __hip_atomic_load(&ctrB[i * 16],
                                             __ATOMIC_RELAXED, __HIP_MEMORY_SCOPE_SYSTEM);
                if (tot >= 128u * 41u) break;
                __builtin_amdgcn_s_sleep(1);
            }
        }
        __syncthreads();

        float sf = 0.f, sg = 0.f, sx = 0.f, sy = 0.f, um = -1e30f, us = 0.f;
        for (int i = tid; i < NPT; i += NTHR) {
            sf += gload(ffin + i); sg += gload(g + i);
            sx += gload(fxv + i);  sy += gload(fyv + i);
            float v = gload(uls + i);
            float mn = fmaxf(um, v);
            us = us * fexp2(um - mn) + fexp2(v - mn);
            um = mn;
        }
#pragma unroll
        for (int off = 1; off < 64; off <<= 1) {
            sf += __shfl_xor(sf, off, 64);
            sg += __shfl_xor(sg, off, 64);
            sx += __shfl_xor(sx, off, 64);
            sy += __shfl_xor(sy, off, 64);
            float mo = __shfl_xor(um, off, 64);
            float so = __shfl_xor(us, off, 64);
            float mn = fmaxf(um, mo);
            us = us * fexp2(um - mn) + so * fexp2(mo - mn);
            um = mn;
        }
        __syncthreads();
        if (lane == 0) {
            float* red = smem;
            red[wave * 6 + 0] = sf; red[wave * 6 + 1] = sg; red[wave * 6 + 2] = sx;
            red[wave * 6 + 3] = sy; red[wave * 6 + 4] = um; red[wave * 6 + 5] = us;
        }
        __syncthreads();
        if (tid == 0) {
            float* red = smem;
            float Sf = 0, Sg = 0, Sx = 0, Sy = 0, Um = -1e30f, Us = 0;
            for (int w = 0; w < 16; ++w) {
                Sf += red[w * 6 + 0]; Sg += red[w * 6 + 1];
                Sx += red[w * 6 + 2]; Sy += red[w * 6 + 3];
                float mo = red[w * 6 + 4], so = red[w * 6 + 5];
                float mn = fmaxf(Um, mo);
                Us = Us * fexp2(Um - mn) + so * fexp2(mo - mn);
                Um = mn;
            }
            float mean = (Sf + Sg - Sx - Sy) * (1.0f / 4096.0f);
            float U = LN2F * (Um + flog2(Us)) - logf(4096.0f * 4095.0f);
            out[0] = mean + U;
        }
    }
}

extern "C" void kernel_launch(void* const* d_in, const int* in_sizes, int n_in,
                              void* d_out, int out_size, void* d_ws, size_t ws_size,
                              hipStream_t stream) {
    const float* x = (const float*)d_in[0];
    const float* y = (const float*)d_in[1];
    float* ws  = (float*)d_ws;
    float* out = (float*)d_out;

    (void)hipFuncSetAttribute((const void*)sink_main,
                              hipFuncAttributeMaxDynamicSharedMemorySize, SMEM_BYTES);

    sink_init<<<4, 1024, 0, stream>>>(ws);
    sink_main<<<NBLK, NTHR, SMEM_BYTES, stream>>>(x, y, ws, out);
}

// Round 9
// 533.789 us; speedup vs baseline: 2.2779x; 2.2779x over previous
//
#include <hip/hip_runtime.h>

#define NPT  4096
#define NBLK 256
#define NTHR 1024

constexpr float EPSV   = 1e-4f;
constexpr float LN2F   = 0.69314718055994531f;
constexpr float E2     = EPSV * LN2F;          // eps*ln2
constexpr float INV_E2 = 1.0f / E2;            // 1/(eps*ln2)
constexpr float S_U    = 4.0f / LN2F;          // uniformity scale

// LDS layout (floats), column-PAIR packed for v_pk_*_f32:
//   pAx : float4[2048] [0,8192)      (x0,x1,y0,y1) of x-point pairs
//   pBx : float4[2048] [8192,16384)  (z0,z1,G0,G1) of x-point pairs
//   pAy : float4[2048] [16384,24576) (x0,x1,y0,y1) of y-point pairs
//   pBy : float4[2048] [24576,32768) (z0,z1,G0,G1) of y-point pairs
//   part2: float2[1024] [32768,34816) per-row (m,s) partials [lrow][half*8+oct]
#define SMEM_FLOATS 34816
#define SMEM_BYTES  (SMEM_FLOATS * 4)

typedef float v2f __attribute__((ext_vector_type(2)));

__device__ __forceinline__ float fexp2(float x) { return __builtin_amdgcn_exp2f(x); }
__device__ __forceinline__ float flog2(float x) { return __builtin_amdgcn_logf(x); }

__device__ __forceinline__ v2f pk_fma(v2f a, v2f b, v2f c) {
    v2f d;
    asm("v_pk_fma_f32 %0, %1, %2, %3" : "=v"(d) : "v"(a), "v"(b), "v"(c));
    return d;
}
__device__ __forceinline__ v2f pk_add(v2f a, v2f b) {
    v2f d;
    asm("v_pk_add_f32 %0, %1, %2" : "=v"(d) : "v"(a), "v"(b));
    return d;
}
__device__ __forceinline__ float max3f(float a, float b, float c) {
    float d;
    asm("v_max3_f32 %0, %1, %2, %3" : "=v"(d) : "v"(a), "v"(b), "v"(c));
    return d;
}

// VALU-only cross-lane via DPP (no LDS pipe).
// 0xB1 quad_perm xor1; 0x4E quad_perm xor2; 0x141 row_half_mirror (8-lane).
template<int CTRL>
__device__ __forceinline__ float dppf(float x) {
    return __int_as_float(__builtin_amdgcn_update_dpp(
        __float_as_int(x), __float_as_int(x), CTRL, 0xF, 0xF, false));
}

// system-scope (sc0 sc1) relaxed accessors: bypass non-coherent XCD L2s.
__device__ __forceinline__ float gload(const float* p) {
    return __hip_atomic_load(p, __ATOMIC_RELAXED, __HIP_MEMORY_SCOPE_SYSTEM);
}
__device__ __forceinline__ void gstore(float* p, float v) {
    __hip_atomic_store(p, v, __ATOMIC_RELAXED, __HIP_MEMORY_SCOPE_SYSTEM);
}

// Fence-free GROUP barrier (128 blocks per group). 256 blocks x 1024 thr
// (1 block/CU) is the proven-safe residency envelope — R8's 2-block/CU
// variant deadlocked at the exact HW limit.
__device__ __forceinline__ void group_barrier(unsigned* base, unsigned target, int b) {
    asm volatile("s_waitcnt vmcnt(0)" ::: "memory");
    __syncthreads();
    if (threadIdx.x == 0) {
        __hip_atomic_fetch_add(&base[(b & 15) * 16], 1u,
                               __ATOMIC_RELAXED, __HIP_MEMORY_SCOPE_SYSTEM);
        for (;;) {
            unsigned tot = 0;
#pragma unroll
            for (int i = 0; i < 16; ++i)
                tot += __hip_atomic_load(&base[i * 16],
                                         __ATOMIC_RELAXED, __HIP_MEMORY_SCOPE_SYSTEM);
            if (tot >= target) break;
            __builtin_amdgcn_s_sleep(1);
        }
    }
    __syncthreads();
}

// One wave: log2-LSE for 2 rows over 2048 columns (1024 pairs, one half).
// R6-verified chunked pk-f32 inner loop (av[2][4] v2f, no spill at 64 VGPR)
// + DPP-8 VALU-only reduction tail (verified in R7) -> 8 partials/row-half.
template<bool ISU>
__device__ __forceinline__ void run_task(
    const float4* __restrict__ cpA, const float4* __restrict__ cpB,
    const float*  __restrict__ rAf, const float*  __restrict__ rBf,
    int r0g, int half, int lane, float scale, float2* part2, int lr0)
{
    v2f xs0[2], xs1[2], xs2[2];
#pragma unroll
    for (int r = 0; r < 2; ++r) {
        const int rr = r0g + r;
        const int pb4 = (rr >> 1) * 4, c0 = rr & 1;
        float xv = rAf[pb4 + c0] * scale;
        float yv = rAf[pb4 + 2 + c0] * scale;
        float zv = rBf[pb4 + c0] * scale;
        xs0[r] = (v2f){xv, xv};
        xs1[r] = (v2f){yv, yv};
        xs2[r] = (v2f){zv, zv};
    }
    float m[2], s[2];
    const int pbase = half * 1024 + lane;
    const float4* colA = cpA + pbase;
    const float4* colB = cpB + pbase;

#pragma unroll
    for (int chunk = 0; chunk < 4; ++chunk) {
        v2f av[2][4];
        float mc[2] = {-1e30f, -1e30f};
#pragma unroll
        for (int k = 0; k < 4; ++k) {
            const float4 a4 = colA[(chunk * 4 + k) * 64];
            const float4 b4 = colB[(chunk * 4 + k) * 64];
            const v2f xx = {a4.x, a4.y}, yy = {a4.z, a4.w};
            const v2f zz = {b4.x, b4.y}, gg = {b4.z, b4.w};
#pragma unroll
            for (int r = 0; r < 2; ++r) {
                v2f a01 = pk_fma(xs2[r], zz, gg);
                a01 = pk_fma(xs1[r], yy, a01);
                a01 = pk_fma(xs0[r], xx, a01);
                if (ISU) {
                    const int p = pbase + (chunk * 4 + k) * 64;
                    const int rr = r0g + r;
                    if (p == (rr >> 1)) {
                        if (rr & 1) a01.y = -1e30f; else a01.x = -1e30f;
                    }
                }
                av[r][k] = a01;
                mc[r] = max3f(mc[r], a01.x, a01.y);
            }
        }
#pragma unroll
        for (int r = 0; r < 2; ++r) {
            const float nm = -mc[r];
            v2f mcn = {nm, nm};
            float sA = 0.0f, sB = 0.0f;
#pragma unroll
            for (int k = 0; k < 4; ++k) {
                v2f d = pk_add(av[r][k], mcn);
                sA += fexp2(d.x);
                sB += fexp2(d.y);
            }
            const float sc_ = sA + sB;
            if (chunk == 0) { m[r] = mc[r]; s[r] = sc_; }
            else {
                float dd = m[r] - mc[r];
                float e = fexp2(-fabsf(dd));
                float bigs   = (dd >= 0.0f) ? s[r] : sc_;
                float smalls = (dd >= 0.0f) ? sc_  : s[r];
                s[r] = fmaf(smalls, e, bigs);
                m[r] = fmaxf(m[r], mc[r]);
            }
        }
    }
    // ---- VALU-only DPP reduction to 8-lane partials (no LDS pipe) ----
#pragma unroll
    for (int r = 0; r < 2; ++r) {
        const float ml = m[r];
        float mm = m[r];
        mm = fmaxf(mm, dppf<0xB1>(mm));
        mm = fmaxf(mm, dppf<0x4E>(mm));
        mm = fmaxf(mm, dppf<0x141>(mm));
        float ssv = s[r] * fexp2(ml - mm);
        ssv += dppf<0xB1>(ssv);
        ssv += dppf<0x4E>(ssv);
        ssv += dppf<0x141>(ssv);
        if ((lane & 7) == 0)
            part2[(lr0 + r) * 16 + half * 8 + (lane >> 3)] = make_float2(mm, ssv);
    }
}

__global__ void sink_init(float* __restrict__ ws) {
    int t = blockIdx.x * blockDim.x + threadIdx.x;
    if (t < NPT) {
        gstore(ws + t, 0.0f);           // f
        gstore(ws + 4096 + t, 0.0f);    // g
        gstore(ws + 8192 + t, 0.0f);    // px0
        gstore(ws + 16384 + t, 0.0f);   // py0
    }
    if (t < 512) {
        __hip_atomic_store((unsigned*)(ws + 40960) + t, 0u,
                           __ATOMIC_RELAXED, __HIP_MEMORY_SCOPE_SYSTEM);
    }
}

__global__ __launch_bounds__(NTHR)
__attribute__((amdgpu_waves_per_eu(4, 4)))
void sink_main(
    const float* __restrict__ xin, const float* __restrict__ yin,
    float* __restrict__ ws, float* __restrict__ out)
{
    extern __shared__ float smem[];
    float4* pAx = (float4*)smem;
    float4* pBx = (float4*)(smem + 8192);
    float4* pAy = (float4*)(smem + 16384);
    float4* pBy = (float4*)(smem + 24576);
    float2* part2 = (float2*)(smem + 32768);

    float* f    = ws;
    float* g    = ws + 4096;
    float* px0  = ws + 8192;
    float* px1  = ws + 12288;
    float* py0  = ws + 16384;
    float* py1  = ws + 20480;
    float* ffin = ws + 24576;
    float* fxv  = ws + 28672;
    float* fyv  = ws + 32768;
    float* uls  = ws + 36864;
    unsigned* ctrA = (unsigned*)(ws + 40960);        // group A (blocks 0-127)
    unsigned* ctrB = (unsigned*)(ws + 40960) + 256;  // group B (blocks 128-255)

    const int tid  = threadIdx.x;
    const int b    = blockIdx.x;
    const int wave = tid >> 6;
    const int lane = tid & 63;
    unsigned* cbarrier = (b < 128) ? ctrA : ctrB;

    // Stage point clouds into pair-packed LDS (G slots filled per step).
    const float4* yin4 = (const float4*)yin;
    for (int i = tid; i < 2048; i += NTHR) {
        float x0 = xin[6 * i + 0], y0v = xin[6 * i + 1], z0 = xin[6 * i + 2];
        float x1 = xin[6 * i + 3], y1v = xin[6 * i + 4], z1 = xin[6 * i + 5];
        pAx[i] = make_float4(x0, x1, y0v, y1v);
        pBx[i] = make_float4(z0, z1, 0.0f, 0.0f);
        float4 v0 = yin4[2 * i], v1 = yin4[2 * i + 1];
        pAy[i] = make_float4(v0.x, v1.x, v0.y, v1.y);
        pBy[i] = make_float4(v0.z, v1.z, 0.0f, 0.0f);
    }
    __syncthreads();

    for (int h = 0; h <= 40; ++h) {
        // ---- decode this block's chain for this step ----
        bool rows_x, cols_x, isU = false, avg = false;
        const float* pot; float* outp; float scale = INV_E2;
        int row0g, rows_pb;
        if (h == 0) {
            if (b < 128)      { rows_x = true;  cols_x = false; pot = g;    outp = f;    rows_pb = 32; row0g = b * 32; }
            else if (b < 192) { rows_x = true;  cols_x = true;  pot = px0;  outp = px1;  avg = true; rows_pb = 64; row0g = (b - 128) * 64; }
            else              { rows_x = true;  cols_x = true;  pot = nullptr; outp = uls; isU = true; scale = S_U; rows_pb = 64; row0g = (b - 192) * 64; }
        } else if (h == 40) {
            if (b < 128)      { rows_x = true;  cols_x = false; pot = g;    outp = ffin; rows_pb = 32; row0g = b * 32; }
            else if (b < 192) { rows_x = true;  cols_x = true;  pot = px0;  outp = fxv;  rows_pb = 64; row0g = (b - 128) * 64; }
            else              { rows_x = false; cols_x = false; pot = py0;  outp = fyv;  rows_pb = 64; row0g = (b - 192) * 64; }
        } else if (h & 1) {
            int k = (h - 1) >> 1;   // yy iteration
            if (b < 128) { rows_x = false; cols_x = true;  pot = f; outp = g; rows_pb = 32; row0g = b * 32; }
            else         { rows_x = false; cols_x = false; pot = (k & 1) ? py1 : py0; outp = (k & 1) ? py0 : py1; avg = true; rows_pb = 32; row0g = (b - 128) * 32; }
        } else {
            int k = h >> 1;         // xx iteration
            if (b < 128) { rows_x = true; cols_x = false; pot = g; outp = f; rows_pb = 32; row0g = b * 32; }
            else         { rows_x = true; cols_x = true;  pot = (k & 1) ? px1 : px0; outp = (k & 1) ? px0 : px1; avg = true; rows_pb = 32; row0g = (b - 128) * 32; }
        }

        // ---- restage G pair (pB[].zw) of the active column pack ----
        float4* cpA = cols_x ? pAx : pAy;
        float4* cpB = cols_x ? pBx : pBy;
        for (int p = tid; p < 2048; p += NTHR) {
            float4 a4 = cpA[p];
            float4 b4 = cpB[p];
            float cn0 = 0.5f * (a4.x * a4.x + a4.z * a4.z + b4.x * b4.x);
            float cn1 = 0.5f * (a4.y * a4.y + a4.w * a4.w + b4.y * b4.y);
            float pv0 = pot ? gload(pot + 2 * p)     : 0.0f;
            float pv1 = pot ? gload(pot + 2 * p + 1) : 0.0f;
            ((float2*)&cpB[p])[1] = make_float2((pv0 - cn0) * scale,
                                                (pv1 - cn1) * scale);
        }
        __syncthreads();

        // ---- wave tasks: 2 rows x 2048 cols each ----
        const float* rAf = (const float*)(rows_x ? pAx : pAy);
        const float* rBf = (const float*)(rows_x ? pBx : pBy);
        const int ntask = rows_pb;
        for (int t = wave; t < ntask; t += 16) {
            int grp = t >> 1, half = t & 1;
            int lr0 = grp << 1;
            int r0g = row0g + lr0;
            if (isU) run_task<true >(cpA, cpB, rAf, rBf, r0g, half, lane, scale, part2, lr0);
            else     run_task<false>(cpA, cpB, rAf, rBf, r0g, half, lane, scale, part2, lr0);
        }
        __syncthreads();

        // ---- finalize: merge 16 partials (max chain + pipelined exp2 sum) ----
        if (tid < rows_pb) {
            float2 pv2[16];
#pragma unroll
            for (int q = 0; q < 16; ++q) pv2[q] = part2[tid * 16 + q];
            float mm = pv2[0].x;
#pragma unroll
            for (int q = 1; q < 15; q += 2) mm = max3f(mm, pv2[q].x, pv2[q + 1].x);
            mm = fmaxf(mm, pv2[15].x);
            float ss = 0.0f;
#pragma unroll
            for (int q = 0; q < 16; ++q) ss += pv2[q].y * fexp2(pv2[q].x - mm);
            int rg = row0g + tid;
            const int pb4 = (rg >> 1) * 4, c0 = rg & 1;
            float xv = rAf[pb4 + c0];
            float yv = rAf[pb4 + 2 + c0];
            float zv = rBf[pb4 + c0];
            float rn = 0.5f * (xv * xv + yv * yv + zv * zv);
            float lse2 = mm + flog2(ss) - rn * scale;    // + X_i
            float val;
            if (isU) {
                val = lse2;
            } else {
                val = -E2 * (lse2 - 12.0f);               // log2(4096)=12
                if (avg) val = 0.5f * (gload(pot + rg) + val);
            }
            gstore(outp + rg, val);
        }

        group_barrier(cbarrier, 128u * (unsigned)(h + 1), b);
    }

    // ---- final reduction (block 0; must also wait for group B) ----
    if (b == 0) {
        if (tid == 0) {
            for (;;) {
                unsigned tot = 0;
#pragma unroll
                for (int i = 0; i < 16; ++i)
                    tot += __hip_atomic_load(&ctrB[i * 16],
                                             __ATOMIC_RELAXED, __HIP_MEMORY_SCOPE_SYSTEM);
                if (tot >= 128u * 41u) break;
                __builtin_amdgcn_s_sleep(1);
            }
        }
        __syncthreads();

        float sf = 0.f, sg = 0.f, sx = 0.f, sy = 0.f, um = -1e30f, us = 0.f;
        for (int i = tid; i < NPT; i += NTHR) {
            sf += gload(ffin + i); sg += gload(g + i);
            sx += gload(fxv + i);  sy += gload(fyv + i);
            float v = gload(uls + i);
            float mn = fmaxf(um, v);
            us = us * fexp2(um - mn) + fexp2(v - mn);
            um = mn;
        }
#pragma unroll
        for (int off = 1; off < 64; off <<= 1) {
            sf += __shfl_xor(sf, off, 64);
            sg += __shfl_xor(sg, off, 64);
            sx += __shfl_xor(sx, off, 64);
            sy += __shfl_xor(sy, off, 64);
            float mo = __shfl_xor(um, off, 64);
            float so = __shfl_xor(us, off, 64);
            float mn = fmaxf(um, mo);
            us = us * fexp2(um - mn) + so * fexp2(mo - mn);
            um = mn;
        }
        __syncthreads();
        if (lane == 0) {
            float* red = smem;
            red[wave * 6 + 0] = sf; red[wave * 6 + 1] = sg; red[wave * 6 + 2] = sx;
            red[wave * 6 + 3] = sy; red[wave * 6 + 4] = um; red[wave * 6 + 5] = us;
        }
        __syncthreads();
        if (tid == 0) {
            float* red = smem;
            float Sf = 0, Sg = 0, Sx = 0, Sy = 0, Um = -1e30f, Us = 0;
            for (int w = 0; w < 16; ++w) {
                Sf += red[w * 6 + 0]; Sg += red[w * 6 + 1];
                Sx += red[w * 6 + 2]; Sy += red[w * 6 + 3];
                float mo = red[w * 6 + 4], so = red[w * 6 + 5];
                float mn = fmaxf(Um, mo);
                Us = Us * fexp2(Um - mn) + so * fexp2(mo - mn);
                Um = mn;
            }
            float mean = (Sf + Sg - Sx - Sy) * (1.0f / 4096.0f);
            float U = LN2F * (Um + flog2(Us)) - logf(4096.0f * 4095.0f);
            out[0] = mean + U;
        }
    }
}

extern "C" void kernel_launch(void* const* d_in, const int* in_sizes, int n_in,
                              void* d_out, int out_size, void* d_ws, size_t ws_size,
                              hipStream_t stream) {
    const float* x = (const float*)d_in[0];
    const float* y = (const float*)d_in[1];
    float* ws  = (float*)d_ws;
    float* out = (float*)d_out;

    (void)hipFuncSetAttribute((const void*)sink_main,
                              hipFuncAttributeMaxDynamicSharedMemorySize, SMEM_BYTES);

    sink_init<<<4, 1024, 0, stream>>>(ws);
    sink_main<<<NBLK, NTHR, SMEM_BYTES, stream>>>(x, y, ws, out);
}